// Round 3
// baseline (239.213 us; speedup 1.0000x reference)
//
#include <hip/hip_runtime.h>
#include <cstdint>

typedef __attribute__((ext_vector_type(8))) short short8;
typedef __attribute__((ext_vector_type(4))) float floatx4;

constexpr int NB = 4;        // batch
constexpr int NV = 8192;     // vertices
constexpr int NF = 16384;    // faces
constexpr int NP = 8192;     // query points per batch
constexpr float F_EPS = 1e-3f;
constexpr float F_WEIGHT = 1000.0f;
constexpr float BIAS = 1e-3f;        // keeps dist^2 > 0 despite bf16-hi/lo rounding

constexpr int PT_TILES = NP / 16;        // 512 point tiles / batch
constexpr int FC_TILES = NF / 16;        // 1024 face tiles / batch
constexpr int TPB = 256;                 // 4 waves
constexpr int TPW = 4;                   // point tiles per wave (64 points/wave)
constexpr int FS = 16;                   // face slices -> 2048 blocks = 8/CU
constexpr int SL_TILES = FC_TILES / FS;  // 64 tiles per slice
constexpr int PGS = NP / 256;            // 32 point groups per batch

union FragU { uint4 u; short8 s; };

__device__ inline unsigned f2bf(float f) {           // fp32 -> bf16 (RNE)
    unsigned u = __float_as_uint(f);
    return (u + 0x7FFFu + ((u >> 16) & 1u)) >> 16;
}
__device__ inline float bf2f(unsigned h) { return __uint_as_float(h << 16); }
__device__ inline unsigned pk(unsigned lo, unsigned hi) {
    return (lo & 0xFFFFu) | (hi << 16);
}

// ---------------------------------------------------------------------------
// Fused prep: faces -> (b_frags, centers4, normals4); points -> a_frags;
// plus all workspace init (keys, acc, tickets). K-slot maps (K=16 used of 32;
// k16..31 are zero and are NOT stored -- only lanes 0..31 per tile, 32*16B):
//  A (point m): k0..2=-2p_hi k3..5=-2p_lo k6..8=-2p_hi k9..11=-2p_lo
//               k12=1 k13=1 k14=p2b_hi k15=p2b_lo
//  B (face n):  k0..2=c_hi  k3..5=c_hi  k6..8=c_lo  k9..11=c_lo
//               k12=c2_hi k13=c2_lo k14=1 k15=1
//  => D[m][n] = p2b[m] + c2[n] - 2 p[m].c[n] = dist^2 + BIAS > 0
// ---------------------------------------------------------------------------
__global__ void prep_kernel(const float* __restrict__ pred,
                            const float* __restrict__ pos,
                            const int*   __restrict__ faces,
                            uint4* __restrict__ a_frags,
                            uint4* __restrict__ b_frags,
                            float4* __restrict__ centers4,
                            float4* __restrict__ normals4,
                            unsigned* __restrict__ keys,
                            float* __restrict__ acc,
                            unsigned* __restrict__ tk) {
    int i = blockIdx.x * blockDim.x + threadIdx.x;   // [0, NB*NF)
    if (i >= NB * NF) return;
    if (i < 2) acc[i] = 0.0f;
    if (i <= NB * PGS) tk[i] = 0u;                   // 128 group tickets + 1 global

    const unsigned ONE = 0x3F80u;

    // ---- faces ----
    {
        int b = i / NF, f = i & (NF - 1);
        const float* p = pos + (size_t)b * NV * 3;
        int i0 = faces[3 * (size_t)i], i1 = faces[3 * (size_t)i + 1], i2 = faces[3 * (size_t)i + 2];
        float ax = p[3 * i0], ay = p[3 * i0 + 1], az = p[3 * i0 + 2];
        float bx = p[3 * i1], by = p[3 * i1 + 1], bz = p[3 * i1 + 2];
        float cx = p[3 * i2], cy = p[3 * i2 + 1], cz = p[3 * i2 + 2];

        const float third = 1.0f / 3.0f;
        float mx = (ax + bx + cx) * third;
        float my = (ay + by + cy) * third;
        float mz = (az + bz + cz) * third;
        float c2 = mx * mx + my * my + mz * mz;

        float e1x = bx - ax, e1y = by - ay, e1z = bz - az;
        float e2x = cx - ax, e2y = cy - ay, e2z = cz - az;
        float nx = e1y * e2z - e1z * e2y;
        float ny = e1z * e2x - e1x * e2z;
        float nz = e1x * e2y - e1y * e2x;
        float len = sqrtf(nx * nx + ny * ny + nz * nz);
        float inv = 1.0f / fmaxf(len, 1e-12f);

        centers4[i] = make_float4(mx, my, mz, c2);
        normals4[i] = make_float4(nx * inv, ny * inv, nz * inv, 0.0f);

        unsigned bhx = f2bf(mx), bhy = f2bf(my), bhz = f2bf(mz);
        unsigned blx = f2bf(mx - bf2f(bhx)), bly = f2bf(my - bf2f(bhy)), blz = f2bf(mz - bf2f(bhz));
        unsigned c2h = f2bf(c2);
        unsigned c2l = f2bf(c2 - bf2f(c2h));

        int tile = f >> 4, n = f & 15;
        uint4* bb = b_frags + (size_t)(b * FC_TILES + tile) * 32;
        bb[n]      = make_uint4(pk(bhx, bhy), pk(bhz, bhx), pk(bhy, bhz), pk(blx, bly)); // k0..7
        bb[16 + n] = make_uint4(pk(blz, blx), pk(bly, blz), pk(c2h, c2l), pk(ONE, ONE)); // k8..15
    }

    // ---- points ----
    if (i < NB * NP) {
        keys[i] = 0xFFFFFFFFu;
        int pb = i / NP, n = i & (NP - 1);
        float x = pred[3 * (size_t)i], y = pred[3 * (size_t)i + 1], z = pred[3 * (size_t)i + 2];
        unsigned hx = f2bf(x), hy = f2bf(y), hz = f2bf(z);
        float rx = x - bf2f(hx), ry = y - bf2f(hy), rz = z - bf2f(hz);
        unsigned ahx = f2bf(-2.f * bf2f(hx)), ahy = f2bf(-2.f * bf2f(hy)), ahz = f2bf(-2.f * bf2f(hz));
        unsigned alx = f2bf(-2.f * rx), aly = f2bf(-2.f * ry), alz = f2bf(-2.f * rz);
        float p2 = x * x + y * y + z * z + BIAS;
        unsigned p2h = f2bf(p2);
        unsigned p2l = f2bf(p2 - bf2f(p2h));

        int tile = n >> 4, m = n & 15;
        uint4* ab = a_frags + (size_t)(pb * PT_TILES + tile) * 32;
        ab[m]      = make_uint4(pk(ahx, ahy), pk(ahz, alx), pk(aly, alz), pk(ahx, ahy)); // k0..7
        ab[16 + m] = make_uint4(pk(ahz, alx), pk(aly, alz), pk(ONE, ONE), pk(p2h, p2l)); // k8..15
    }
}

// ---------------------------------------------------------------------------
// 1-NN scan on the matrix pipe, LDS-free streaming + fused finalize/output.
// Block = (point group of 256 pts, face slice, batch). B-frags stream from
// L2 (coalesced dwordx4, lanes 0..31 only; upper lanes stay zero). Epilogue
// per face-tile PAIR: 8 v_and_or_b32 + 4 v_min3_u32 on packed keys
//   key = (bits(dist^2+BIAS) & 0xFFFFC000) | face_idx   (14 idx bits)
// Cross-slice merge via atomicMin; last slice-block per (b,pg) finalizes its
// 256 points; last finalizer overall writes d_out. 2 dispatches total.
// ---------------------------------------------------------------------------
__global__ __launch_bounds__(TPB, 8) void nn_kernel(
        const float* __restrict__ pred,
        const uint4* __restrict__ a_frags,
        const uint4* __restrict__ b_frags,
        const float4* __restrict__ centers4,
        const float4* __restrict__ normals4,
        unsigned* __restrict__ keys,
        float* __restrict__ acc,
        unsigned* __restrict__ tk,
        float* __restrict__ out) {
    const int pg = blockIdx.x, sl = blockIdx.y, b = blockIdx.z;
    const int tid = threadIdx.x, wave = tid >> 6, lane = tid & 63, col = lane & 15;

    __shared__ unsigned s_tkt;
    __shared__ float sv[4], sn[4];

    FragU a[TPW], b0, b1;
    const uint4 z4 = make_uint4(0u, 0u, 0u, 0u);
#pragma unroll
    for (int t = 0; t < TPW; ++t) a[t].u = z4;
    b0.u = z4; b1.u = z4;

    const int base_t = b * PT_TILES + pg * 16 + wave * TPW;
    if (lane < 32) {
#pragma unroll
        for (int t = 0; t < TPW; ++t)
            a[t].u = a_frags[(size_t)(base_t + t) * 32 + lane];
    }

    unsigned best[TPW * 4];
#pragma unroll
    for (int e = 0; e < TPW * 4; ++e) best[e] = 0xFFFFFFFFu;

    const floatx4 zero = {0.f, 0.f, 0.f, 0.f};
    const uint4* bptr = b_frags + (size_t)(b * FC_TILES + sl * SL_TILES) * 32;
    unsigned vf = (unsigned)(sl * SL_TILES * 16 + col);

    for (int t = 0; t < SL_TILES; t += 2) {
        if (lane < 32) {
            b0.u = bptr[t * 32 + lane];
            b1.u = bptr[t * 32 + 32 + lane];
        }
#pragma unroll
        for (int tt = 0; tt < TPW; ++tt) {
            floatx4 d0 = __builtin_amdgcn_mfma_f32_16x16x32_bf16(a[tt].s, b0.s, zero, 0, 0, 0);
            floatx4 d1 = __builtin_amdgcn_mfma_f32_16x16x32_bf16(a[tt].s, b1.s, zero, 0, 0, 0);
#pragma unroll
            for (int r = 0; r < 4; ++r) {
                unsigned k0 = (__float_as_uint(d0[r]) & 0xFFFFC000u) | vf;
                unsigned k1 = (__float_as_uint(d1[r]) & 0xFFFFC000u) | (vf + 16u);
                unsigned m01 = k0 < k1 ? k0 : k1;            // umin
                unsigned bb  = best[tt * 4 + r];
                best[tt * 4 + r] = m01 < bb ? m01 : bb;      // -> v_min3_u32
            }
        }
        vf += 32u;
    }

    // reduce across the 16 columns (lanes sharing a quad), then atomicMin
#pragma unroll
    for (int e = 0; e < TPW * 4; ++e) {
        unsigned v = best[e];
#pragma unroll
        for (int m = 1; m < 16; m <<= 1) {
            unsigned s = (unsigned)__shfl_xor((int)v, m, 64);
            v = s < v ? s : v;
        }
        best[e] = v;
    }
    unsigned* kb = keys + b * NP;
    if (col == 0) {
        int q = lane >> 4;
#pragma unroll
        for (int tt = 0; tt < TPW; ++tt)
#pragma unroll
            for (int r = 0; r < 4; ++r) {
                int n = (pg * 16 + wave * TPW + tt) * 16 + q * 4 + r;
                atomicMin(&kb[n], best[tt * 4 + r]);
            }
    }

    // ---- ticket: last slice-block for this (b,pg) finalizes its 256 points
    __threadfence();
    __syncthreads();                       // all atomicMins of this block done
    if (tid == 0) s_tkt = atomicAdd(&tk[b * PGS + pg], 1u);
    __syncthreads();
    if (s_tkt == FS - 1) {
        const int i = b * NP + pg * 256 + tid;
        unsigned key = __hip_atomic_load(&keys[i], __ATOMIC_RELAXED, __HIP_MEMORY_SCOPE_AGENT);
        int idx = (int)(key & (unsigned)(NF - 1));
        float4 c  = centers4[b * NF + idx];
        float4 nr = normals4[b * NF + idx];
        float dx = pred[3 * (size_t)i]     - c.x;
        float dy = pred[3 * (size_t)i + 1] - c.y;
        float dz = pred[3 * (size_t)i + 2] - c.z;
        float dist = dx * nr.x + dy * nr.y + dz * nr.z;
        float tpos = F_EPS - dist;
        float val = 0.0f, cnt = 0.0f;
        if (tpos > 0.0f) { cnt = 1.0f; val = tpos * tpos * tpos; }
        for (int off = 32; off > 0; off >>= 1) {
            val += __shfl_down(val, off, 64);
            cnt += __shfl_down(cnt, off, 64);
        }
        if (lane == 0) { sv[wave] = val; sn[wave] = cnt; }
        __syncthreads();
        if (tid == 0) {
            float v  = sv[0] + sv[1] + sv[2] + sv[3];
            float cc = sn[0] + sn[1] + sn[2] + sn[3];
            atomicAdd(&acc[0], v);
            atomicAdd(&acc[1], cc);
            __threadfence();
            unsigned t2 = atomicAdd(&tk[NB * PGS], 1u);
            if (t2 == (unsigned)(NB * PGS - 1)) {   // last finalizer writes out
                float a0 = __hip_atomic_load(&acc[0], __ATOMIC_RELAXED, __HIP_MEMORY_SCOPE_AGENT);
                float a1 = __hip_atomic_load(&acc[1], __ATOMIC_RELAXED, __HIP_MEMORY_SCOPE_AGENT);
                out[0] = a0 * (F_WEIGHT / (float)NB);
                out[1] = a1 * (1.0f / (float)(NB * NP));
            }
        }
    }
}

extern "C" void kernel_launch(void* const* d_in, const int* in_sizes, int n_in,
                              void* d_out, int out_size, void* d_ws, size_t ws_size,
                              hipStream_t stream) {
    const float* pred  = (const float*)d_in[0];   // [B,N,3] f32
    const float* opos  = (const float*)d_in[1];   // [B,V,3] f32
    const int*   faces = (const int*)  d_in[2];   // [B,F,3] i32

    char* ws = (char*)d_ws;
    const size_t a_bytes = (size_t)NB * PT_TILES * 32 * 16;   // 1 MiB
    const size_t b_bytes = (size_t)NB * FC_TILES * 32 * 16;   // 2 MiB
    const size_t c_bytes = (size_t)NB * NF * 16;              // 1 MiB
    const size_t k_bytes = (size_t)NB * NP * sizeof(unsigned);// 128 KiB

    uint4*    a_frags  = (uint4*)ws;
    uint4*    b_frags  = (uint4*)(ws + a_bytes);
    float4*   centers4 = (float4*)(ws + a_bytes + b_bytes);
    float4*   normals4 = (float4*)(ws + a_bytes + b_bytes + c_bytes);
    unsigned* keys     = (unsigned*)(ws + a_bytes + b_bytes + 2 * c_bytes);
    unsigned* tk       = (unsigned*)(ws + a_bytes + b_bytes + 2 * c_bytes + k_bytes);
    float*    acc      = (float*)(ws + a_bytes + b_bytes + 2 * c_bytes + k_bytes +
                                  ((size_t)(NB * PGS + 1) * sizeof(unsigned) + 15) / 16 * 16);

    prep_kernel<<<(NB * NF + TPB - 1) / TPB, TPB, 0, stream>>>(
        pred, opos, faces, a_frags, b_frags, centers4, normals4, keys, acc, tk);

    nn_kernel<<<dim3(PGS, FS, NB), TPB, 0, stream>>>(
        pred, a_frags, b_frags, centers4, normals4, keys, acc, tk, (float*)d_out);
}